// Round 2
// baseline (9421.453 us; speedup 1.0000x reference)
//
#include <hip/hip_runtime.h>

// minGRU scan: h_t = exp(lc[t-1]) * h_{t-1} + exp(lv[t]);  out = h_1..h_T.
//
// v3: chunked scan + decoupled lookback (hardened).
// The serial kernel is latency-bound at 1 wave/CU (256 waves, 2.3 TB/s of an
// achievable 6.3). Split T into C=128 chunks of U=32: each block handles
// (channel_group g, chunk c), computes the affine composition
//   h_{t0+u+1} = p_u * h_in + l_u
// entirely in registers, resolves h_in by spinning on the predecessor chunk's
// published inclusive state, then emits outputs as independent fmas.
//
// Hardening vs v2 (which killed the container, suspected OOB under rocprof
// kernel-only replay):
//  - ticket is MASKED to [0, NG*C): counter never drives c out of range even
//    if the zeroing memset is not replayed. NG*C is a power of two and each
//    launch issues exactly NG*C tickets, so the counter stays == 0 mod NG*C
//    at launch boundaries -> c-major ticket ordering (deadlock-freedom) holds.
//  - carry sentinel is a bit-exact uint compare (0xFFFFFFFF from the 0xFF
//    memset), immune to fast-math folding of NaN checks. All legit h values
//    are positive finite floats, so no collision.
//  - agent-scope acquire/release atomics (per-XCD L2s are not coherent).

constexpr int Bdim  = 16;
constexpr int Tdim  = 4096;
constexpr int Hdim  = 1024;
constexpr int NCHAN = Bdim * Hdim;      // 16384 channels

constexpr int U   = 32;                 // timesteps per chunk
constexpr int C   = Tdim / U;           // 128 chunks per channel
constexpr int TPB = 256;                // channels per block
constexpr int NG  = NCHAN / TPB;        // 64 channel groups
constexpr unsigned NVB = (unsigned)NG * C;   // 8192 virtual blocks
static_assert((NVB & (NVB - 1)) == 0, "ticket mask requires pow2");
static_assert((NG & (NG - 1)) == 0, "g-extract requires pow2");

constexpr unsigned SENTINEL = 0xFFFFFFFFu;   // NaN bit pattern from 0xFF fill

__global__ __launch_bounds__(TPB, 4)
void mingru_lookback(const float* __restrict__ lc,   // (B, T, H)
                     const float* __restrict__ lv,   // (B, T+1, H)
                     float* __restrict__ out,        // (B, T, H)
                     unsigned int* __restrict__ Hws, // C * NCHAN uints
                     unsigned int* __restrict__ counter) {
  __shared__ unsigned int vb_sh;
  const int tid = threadIdx.x;
  if (tid == 0) vb_sh = atomicAdd(counter, 1u) & (NVB - 1u);
  __syncthreads();
  const unsigned vb = vb_sh;
  const int g = vb & (NG - 1);     // channel group: fast-varying
  const int c = vb >> 6;           // chunk index: bands fill in ticket order

  const int chan = g * TPB + tid;  // consecutive lanes -> consecutive h
  const int b = chan >> 10;        // / Hdim
  const int h = chan & (Hdim - 1);
  const int t0 = c * U;

  const float* lcp = lc + ((size_t)b * Tdim       + t0    ) * Hdim + h;
  const float* lvp = lv + ((size_t)b * (Tdim + 1) + t0 + 1) * Hdim + h;
  float*       op  = out + ((size_t)b * Tdim      + t0    ) * Hdim + h;

  // Issue all chunk loads up front (64 x 4B, wave-coalesced 256B segments).
  float cR[U], vR[U];
#pragma unroll
  for (int u = 0; u < U; ++u) {
    cR[u] = lcp[(size_t)u * Hdim];
    vR[u] = lvp[(size_t)u * Hdim];
  }

  // h_0, only consumed by chunk 0 (load overlaps with the above).
  float h0 = 0.0f;
  if (c == 0) h0 = __expf(lv[(size_t)b * (Tdim + 1) * Hdim + h]);

  // Local affine scan with zero initial state: h_{t0+u+1} = pA[u]*h_in + lA[u]
  float pA[U], lA[U];
  {
    float p = 1.0f, l = 0.0f;
#pragma unroll
    for (int u = 0; u < U; ++u) {
      const float ec = __expf(cR[u]);
      const float ev = __expf(vR[u]);
      p *= ec;                             // prefix product of coefficients
      l = __builtin_fmaf(ec, l, ev);       // local scan term
      pA[u] = p;
      lA[u] = l;
    }
  }

  // Resolve carry-in: spin on predecessor's inclusive state.
  float Hprev;
  if (c == 0) {
    Hprev = h0;
  } else {
    unsigned int* slot = Hws + (size_t)(c - 1) * NCHAN + chan;
    unsigned int uv =
        __hip_atomic_load(slot, __ATOMIC_ACQUIRE, __HIP_MEMORY_SCOPE_AGENT);
    while (uv == SENTINEL) {
      __builtin_amdgcn_s_sleep(2);
      uv = __hip_atomic_load(slot, __ATOMIC_ACQUIRE, __HIP_MEMORY_SCOPE_AGENT);
    }
    Hprev = __uint_as_float(uv);
  }

  // Publish our inclusive state immediately (one fma after observe).
  const float Hc = __builtin_fmaf(pA[U - 1], Hprev, lA[U - 1]);
  __hip_atomic_store(Hws + (size_t)c * NCHAN + chan, __float_as_uint(Hc),
                     __ATOMIC_RELEASE, __HIP_MEMORY_SCOPE_AGENT);

  // Output phase: fully independent fmas, coalesced stores.
#pragma unroll
  for (int u = 0; u < U - 1; ++u) {
    op[(size_t)u * Hdim] = __builtin_fmaf(pA[u], Hprev, lA[u]);
  }
  op[(size_t)(U - 1) * Hdim] = Hc;
}

// ---------------------------------------------------------------------------
// Fallback: previous verified serial kernel (1 thread per channel), used only
// if the workspace is too small for the lookback state.
// ---------------------------------------------------------------------------
constexpr int FU    = 32;
constexpr int FNBLK = Tdim / FU;

__global__ __launch_bounds__(64, 1)
void mingru_scan(const float* __restrict__ lc,
                 const float* __restrict__ lv,
                 float* __restrict__ out) {
  const int chan = blockIdx.x * 64 + threadIdx.x;
  const int b = chan >> 10;
  const int h = chan & (Hdim - 1);

  const float* lcp = lc  + (size_t)b * Tdim       * Hdim + h;
  const float* lvp = lv  + (size_t)b * (Tdim + 1) * Hdim + h;
  float*       op  = out + (size_t)b * Tdim       * Hdim + h;

  float state = __expf(lvp[0]);

  float cA[FU], vA[FU], cB[FU], vB[FU];

#pragma unroll
  for (int u = 0; u < FU; ++u) {
    cA[u] = lcp[(size_t)u * Hdim];
    vA[u] = lvp[(size_t)(u + 1) * Hdim];
  }

  auto tile_lc = [&](float (&cc)[FU], float (&cv)[FU],
                     float (&nc)[FU], float (&nv)[FU], int ibc) {
    const float* pc = lcp + ((size_t)(ibc + 1) * FU) * Hdim;
    const float* pv = lvp + ((size_t)(ibc + 1) * FU + 1) * Hdim;
    float*       po = op  + ((size_t)ibc * FU) * Hdim;
#pragma unroll
    for (int u = 0; u < FU; ++u) {
      nc[u] = pc[(size_t)u * Hdim];
      nv[u] = pv[(size_t)u * Hdim];
      state = __builtin_fmaf(__expf(cc[u]), state, __expf(cv[u]));
      po[(size_t)u * Hdim] = state;
    }
  };

  auto tile_c = [&](float (&cc)[FU], float (&cv)[FU], int ibc) {
    float* po = op + ((size_t)ibc * FU) * Hdim;
#pragma unroll
    for (int u = 0; u < FU; ++u) {
      state = __builtin_fmaf(__expf(cc[u]), state, __expf(cv[u]));
      po[(size_t)u * Hdim] = state;
    }
  };

  for (int ib = 0; ib < FNBLK - 2; ib += 2) {
    tile_lc(cA, vA, cB, vB, ib);
    tile_lc(cB, vB, cA, vA, ib + 1);
  }
  tile_lc(cA, vA, cB, vB, FNBLK - 2);
  tile_c(cB, vB, FNBLK - 1);
}

// ---------------------------------------------------------------------------
extern "C" void kernel_launch(void* const* d_in, const int* in_sizes, int n_in,
                              void* d_out, int out_size, void* d_ws, size_t ws_size,
                              hipStream_t stream) {
  const float* lc  = (const float*)d_in[0];
  const float* lv  = (const float*)d_in[1];
  float*       out = (float*)d_out;

  const size_t h_bytes = (size_t)C * NCHAN * sizeof(unsigned int);   // 8 MiB
  const size_t need    = h_bytes + sizeof(unsigned int);

  if (d_ws != nullptr && ws_size >= need) {
    unsigned int* Hws = (unsigned int*)d_ws;
    unsigned int* counter = (unsigned int*)((char*)d_ws + h_bytes);
    // Sentinel-fill the carry slots (0xFF bytes) and zero the ticket counter.
    hipMemsetAsync(Hws, 0xFF, h_bytes, stream);
    hipMemsetAsync(counter, 0, sizeof(unsigned int), stream);
    hipLaunchKernelGGL(mingru_lookback, dim3(NVB), dim3(TPB), 0, stream,
                       lc, lv, out, Hws, counter);
  } else {
    dim3 grid(NCHAN / 64), block(64);
    hipLaunchKernelGGL(mingru_scan, grid, block, 0, stream, lc, lv, out);
  }
}